// Round 1
// baseline (140.373 us; speedup 1.0000x reference)
//
#include <hip/hip_runtime.h>
#include <hip/hip_bf16.h>

#define NROWS 8192
#define DIM 256
#define NCLS 100
#define NCLS_PAD 128
#define TEMP 0.7f
#define EPSV 1e-8f

// ---------------- kernel 1: scatter-add prototype sums + row inv-norms ----------------
// wave per row: 64 lanes x float4 = 256 dims, coalesced 16B/lane.
__global__ __launch_bounds__(256) void k_scatter(const float* __restrict__ f,
                                                 const int* __restrict__ labels,
                                                 float* __restrict__ protosum,
                                                 int* __restrict__ cnt,
                                                 float* __restrict__ invf) {
    int wave = threadIdx.x >> 6;
    int lane = threadIdx.x & 63;
    int row  = blockIdx.x * 4 + wave;
    float4 v = ((const float4*)f)[row * (DIM / 4) + lane];
    int c = labels[row];
    float* base = protosum + c * DIM + lane * 4;
    atomicAdd(base + 0, v.x);
    atomicAdd(base + 1, v.y);
    atomicAdd(base + 2, v.z);
    atomicAdd(base + 3, v.w);
    float ss = v.x * v.x + v.y * v.y + v.z * v.z + v.w * v.w;
    #pragma unroll
    for (int m = 32; m > 0; m >>= 1) ss += __shfl_xor(ss, m);
    if (lane == 0) {
        atomicAdd(cnt + c, 1);
        invf[row] = 1.0f / fmaxf(sqrtf(ss), EPSV);
    }
}

// ---------------- kernel 2: finalize prototypes ----------------
// block per (padded) class: mean, norm via LDS reduce, pre-fold 1/(norm*T).
__global__ __launch_bounds__(256) void k_proto(const float* __restrict__ protosum,
                                               const int* __restrict__ cnt,
                                               float* __restrict__ protoScaled,
                                               float* __restrict__ countf) {
    int c = blockIdx.x;
    int t = threadIdx.x;
    __shared__ float red[256];
    float s = 0.0f;
    int n = 0;
    if (c < NCLS) {
        n = cnt[c];
        s = protosum[c * DIM + t] / fmaxf((float)n, 1.0f);
    }
    red[t] = s * s;
    __syncthreads();
    #pragma unroll
    for (int m = 128; m > 0; m >>= 1) {
        if (t < m) red[t] += red[t + m];
        __syncthreads();
    }
    float pn = sqrtf(red[0]);
    float scale = 1.0f / (fmaxf(pn, EPSV) * TEMP);
    protoScaled[c * DIM + t] = s * scale;   // zero rows for padded classes
    if (t == 0) countf[c] = (float)n;
}

// ---------------- kernel 3: dots + contrastive reduction ----------------
// 128 blocks x 256 thr; block: 64 rows x 128 classes, BK=32 LDS-staged fp32 GEMM,
// 4x8 register tile per thread; epilogue does count*exp, row-sum, log, diag.
#define BM 64
#define BK 32
#define LDST 36  // +4 pad: 2-way LDS aliasing only (free per m136)

__global__ __launch_bounds__(256) void k_main(const float* __restrict__ f,
                                              const int* __restrict__ labels,
                                              const float* __restrict__ protoScaled,
                                              const float* __restrict__ countf,
                                              const float* __restrict__ invf,
                                              float* __restrict__ out) {
    __shared__ __attribute__((aligned(16))) float fT[BM * LDST];
    __shared__ __attribute__((aligned(16))) float pT[NCLS_PAD * LDST];
    __shared__ float rs[BM * 17];
    __shared__ float dg[BM];

    int tid = threadIdx.x;
    int rb  = blockIdx.x * BM;
    int tx  = tid & 15;   // class lane: classes tx + 16k
    int ty  = tid >> 4;   // row group: rows ty*4 + j

    float acc[4][8];
    #pragma unroll
    for (int j = 0; j < 4; ++j)
        #pragma unroll
        for (int k = 0; k < 8; ++k) acc[j][k] = 0.0f;

    for (int kc = 0; kc < DIM; kc += BK) {
        // stage f tile: 64 x 32
        #pragma unroll
        for (int pass = 0; pass < 2; ++pass) {
            int r  = pass * 32 + (tid >> 3);
            int c4 = tid & 7;
            float4 v = *(const float4*)&f[(rb + r) * DIM + kc + c4 * 4];
            *(float4*)&fT[r * LDST + c4 * 4] = v;
        }
        // stage proto tile: 128 x 32
        #pragma unroll
        for (int pass = 0; pass < 4; ++pass) {
            int c  = pass * 32 + (tid >> 3);
            int c4 = tid & 7;
            float4 v = *(const float4*)&protoScaled[c * DIM + kc + c4 * 4];
            *(float4*)&pT[c * LDST + c4 * 4] = v;
        }
        __syncthreads();
        #pragma unroll
        for (int d4 = 0; d4 < 8; ++d4) {
            float4 fv[4], pv[8];
            #pragma unroll
            for (int j = 0; j < 4; ++j)
                fv[j] = *(const float4*)&fT[(ty * 4 + j) * LDST + d4 * 4];
            #pragma unroll
            for (int k = 0; k < 8; ++k)
                pv[k] = *(const float4*)&pT[(tx + 16 * k) * LDST + d4 * 4];
            #pragma unroll
            for (int j = 0; j < 4; ++j)
                #pragma unroll
                for (int k = 0; k < 8; ++k) {
                    acc[j][k] += fv[j].x * pv[k].x;
                    acc[j][k] += fv[j].y * pv[k].y;
                    acc[j][k] += fv[j].z * pv[k].z;
                    acc[j][k] += fv[j].w * pv[k].w;
                }
        }
        __syncthreads();
    }

    // epilogue
    float invfr[4];
    int lab[4];
    #pragma unroll
    for (int j = 0; j < 4; ++j) {
        invfr[j] = invf[rb + ty * 4 + j];
        lab[j]   = labels[rb + ty * 4 + j];
    }
    float cf[8];
    #pragma unroll
    for (int k = 0; k < 8; ++k) cf[k] = countf[tx + 16 * k];

    #pragma unroll
    for (int j = 0; j < 4; ++j) {
        float rp = 0.0f;
        #pragma unroll
        for (int k = 0; k < 8; ++k) {
            int c = tx + 16 * k;
            float a = acc[j][k] * invfr[j];      // sim/T for (row, class c)
            rp += cf[k] * __expf(a);             // padded classes: cf==0, a==0
            if (c == lab[j]) dg[ty * 4 + j] = a; // unique thread per row
        }
        rs[(ty * 4 + j) * 17 + tx] = rp;
    }
    __syncthreads();

    if (tid < 64) {
        float s = 0.0f;
        #pragma unroll
        for (int x = 0; x < 16; ++x) s += rs[tid * 17 + x];
        float lossr = __logf(s) - dg[tid];
        #pragma unroll
        for (int m = 32; m > 0; m >>= 1) lossr += __shfl_xor(lossr, m);
        if (tid == 0) atomicAdd(out, lossr * (1.0f / (float)NROWS));
    }
}

// ---------------- launch ----------------
// ws layout (floats): [0,25600) protosum | [25600,25728) countf |
// [25728,25828) cnt(int) | [25856,34048) invf | [34048,66816) protoScaled
extern "C" void kernel_launch(void* const* d_in, const int* in_sizes, int n_in,
                              void* d_out, int out_size, void* d_ws, size_t ws_size,
                              hipStream_t stream) {
    const float* f      = (const float*)d_in[0];
    const int*   labels = (const int*)d_in[1];
    float* ws          = (float*)d_ws;
    float* protosum    = ws;
    float* countf      = ws + 25600;
    int*   cnt         = (int*)(ws + 25728);
    float* invf        = ws + 25856;
    float* protoScaled = ws + 34048;

    hipMemsetAsync(d_ws, 0, 25856 * sizeof(float), stream);  // protosum + countf + cnt
    hipMemsetAsync(d_out, 0, sizeof(float), stream);

    k_scatter<<<NROWS / 4, 256, 0, stream>>>(f, labels, protosum, cnt, invf);
    k_proto<<<NCLS_PAD, 256, 0, stream>>>(protosum, cnt, protoScaled, countf);
    k_main<<<NROWS / BM, 256, 0, stream>>>(f, labels, protoScaled, countf, invf,
                                           (float*)d_out);
}

// Round 2
// 95.578 us; speedup vs baseline: 1.4687x; 1.4687x over previous
//
#include <hip/hip_runtime.h>
#include <hip/hip_bf16.h>

#define NROWS 8192
#define DIM 256
#define NCLS 100
#define NCLS_PAD 128
#define TEMP 0.7f
#define EPSV 1e-8f
#define NSPLIT 8
#define RPS (NROWS / NSPLIT)  // 1024 rows per split

// ---------------- kernel 1: class-major gather of prototype sums + row inv-norms ----
// grid (100, 8): block (c,s) scans rows [s*1024,(s+1)*1024), builds match list,
// accumulates per-dim register sums, ONE global atomic per dim (8-way contention).
__global__ __launch_bounds__(256) void k_gather(const float* __restrict__ f,
                                                const int* __restrict__ labels,
                                                float* __restrict__ protosum,
                                                int* __restrict__ cnt,
                                                float* __restrict__ invf) {
    int c    = blockIdx.x;
    int base = blockIdx.y * RPS;
    int tid  = threadIdx.x;
    __shared__ int list[RPS];
    __shared__ int nmatch;
    if (tid == 0) nmatch = 0;
    __syncthreads();
    #pragma unroll
    for (int r = tid; r < RPS; r += 256) {
        if (labels[base + r] == c) list[atomicAdd(&nmatch, 1)] = base + r;
    }
    __syncthreads();
    int n = nmatch;
    // per-dim accumulation: thread t owns dim t; 4-deep unroll for MLP
    float acc = 0.0f;
    int i = 0;
    for (; i + 4 <= n; i += 4) {
        int r0 = list[i], r1 = list[i + 1], r2 = list[i + 2], r3 = list[i + 3];
        float a0 = f[r0 * DIM + tid], a1 = f[r1 * DIM + tid];
        float a2 = f[r2 * DIM + tid], a3 = f[r3 * DIM + tid];
        acc += (a0 + a1) + (a2 + a3);
    }
    for (; i < n; ++i) acc += f[list[i] * DIM + tid];
    if (n > 0) {
        atomicAdd(&protosum[c * DIM + tid], acc);
        if (tid == 0) atomicAdd(cnt + c, n);
    }
    // row inv-norms: wave w takes list entries i == w (mod 4); rows are L1/L2-hot
    int wave = tid >> 6, lane = tid & 63;
    for (int j = wave; j < n; j += 4) {
        int row  = list[j];
        float4 v = ((const float4*)f)[row * (DIM / 4) + lane];
        float ss = v.x * v.x + v.y * v.y + v.z * v.z + v.w * v.w;
        #pragma unroll
        for (int m = 32; m > 0; m >>= 1) ss += __shfl_xor(ss, m);
        if (lane == 0) invf[row] = 1.0f / fmaxf(sqrtf(ss), EPSV);
    }
}

// ---------------- kernel 2: finalize prototypes ----------------
__global__ __launch_bounds__(256) void k_proto(const float* __restrict__ protosum,
                                               const int* __restrict__ cnt,
                                               float* __restrict__ protoScaled,
                                               float* __restrict__ countf) {
    int c = blockIdx.x;
    int t = threadIdx.x;
    __shared__ float red[256];
    float s = 0.0f;
    int n = 0;
    if (c < NCLS) {
        n = cnt[c];
        s = protosum[c * DIM + t] / fmaxf((float)n, 1.0f);
    }
    red[t] = s * s;
    __syncthreads();
    #pragma unroll
    for (int m = 128; m > 0; m >>= 1) {
        if (t < m) red[t] += red[t + m];
        __syncthreads();
    }
    float pn = sqrtf(red[0]);
    float scale = 1.0f / (fmaxf(pn, EPSV) * TEMP);
    protoScaled[c * DIM + t] = s * scale;   // padded classes write zeros
    if (t == 0) countf[c] = (float)n;
}

// ---------------- kernel 3: dots + contrastive reduction ----------------
// 256 blocks x 256 thr; block: 32 rows x 128 classes, BK=32, 4x4 tile/thread.
// fv reads are half-wave broadcasts (free); pv reads ~4-phase b128 (floor-ish).
#define BM 32
#define BK 32
#define LDST 36  // 36 floats = 144 B: 16B-aligned rows, breaks pow-2 stride

__global__ __launch_bounds__(256) void k_main(const float* __restrict__ f,
                                              const int* __restrict__ labels,
                                              const float* __restrict__ protoScaled,
                                              const float* __restrict__ countf,
                                              const float* __restrict__ invf,
                                              float* __restrict__ out) {
    __shared__ __attribute__((aligned(16))) float fT[BM * LDST];
    __shared__ __attribute__((aligned(16))) float pT[NCLS_PAD * LDST];
    __shared__ float rs[BM * 33];
    __shared__ float dg[BM];

    int tid = threadIdx.x;
    int rb  = blockIdx.x * BM;
    int tx  = tid & 31;   // classes tx + 32k, k=0..3
    int ty  = tid >> 5;   // rows ty*4 + j, j=0..3

    float acc[4][4];
    #pragma unroll
    for (int j = 0; j < 4; ++j)
        #pragma unroll
        for (int k = 0; k < 4; ++k) acc[j][k] = 0.0f;

    for (int kc = 0; kc < DIM; kc += BK) {
        {   // stage f tile: 32x32 = 256 float4, one per thread
            int r = tid >> 3, c4 = tid & 7;
            *(float4*)&fT[r * LDST + c4 * 4] =
                *(const float4*)&f[(rb + r) * DIM + kc + c4 * 4];
        }
        #pragma unroll
        for (int p = 0; p < 4; ++p) {  // stage proto tile: 128x32, four per thread
            int cc = p * 32 + (tid >> 3), c4 = tid & 7;
            *(float4*)&pT[cc * LDST + c4 * 4] =
                *(const float4*)&protoScaled[cc * DIM + kc + c4 * 4];
        }
        __syncthreads();
        #pragma unroll
        for (int d4 = 0; d4 < 8; ++d4) {
            float4 fv[4], pv[4];
            #pragma unroll
            for (int j = 0; j < 4; ++j)
                fv[j] = *(const float4*)&fT[(ty * 4 + j) * LDST + d4 * 4];
            #pragma unroll
            for (int k = 0; k < 4; ++k)
                pv[k] = *(const float4*)&pT[(tx + 32 * k) * LDST + d4 * 4];
            #pragma unroll
            for (int j = 0; j < 4; ++j)
                #pragma unroll
                for (int k = 0; k < 4; ++k) {
                    acc[j][k] += fv[j].x * pv[k].x;
                    acc[j][k] += fv[j].y * pv[k].y;
                    acc[j][k] += fv[j].z * pv[k].z;
                    acc[j][k] += fv[j].w * pv[k].w;
                }
        }
        __syncthreads();
    }

    // epilogue: count*exp, row sums, log, diag, block-level loss partial
    float invfr[4];
    int lab[4];
    #pragma unroll
    for (int j = 0; j < 4; ++j) {
        invfr[j] = invf[rb + ty * 4 + j];
        lab[j]   = labels[rb + ty * 4 + j];
    }
    float cf[4];
    #pragma unroll
    for (int k = 0; k < 4; ++k) cf[k] = countf[tx + 32 * k];

    #pragma unroll
    for (int j = 0; j < 4; ++j) {
        float rp = 0.0f;
        #pragma unroll
        for (int k = 0; k < 4; ++k) {
            int c = tx + 32 * k;
            float a = acc[j][k] * invfr[j];       // sim/T for (row, class c)
            rp += cf[k] * __expf(a);              // padded classes: cf==0
            if (c == lab[j]) dg[ty * 4 + j] = a;  // unique writer per row
        }
        rs[(ty * 4 + j) * 33 + tx] = rp;
    }
    __syncthreads();

    if (tid < 32) {
        float s = 0.0f;
        #pragma unroll
        for (int x = 0; x < 32; ++x) s += rs[tid * 33 + x];
        float lossr = __logf(s) - dg[tid];
        #pragma unroll
        for (int m = 16; m > 0; m >>= 1) lossr += __shfl_xor(lossr, m);
        if (tid == 0) atomicAdd(out, lossr * (1.0f / (float)NROWS));
    }
}

// ---------------- launch ----------------
// ws floats: [0,25600) protosum | [25600,25728) countf | [25728,25828) cnt(int)
//          | [25856,34048) invf | [34048,66816) protoScaled
extern "C" void kernel_launch(void* const* d_in, const int* in_sizes, int n_in,
                              void* d_out, int out_size, void* d_ws, size_t ws_size,
                              hipStream_t stream) {
    const float* f      = (const float*)d_in[0];
    const int*   labels = (const int*)d_in[1];
    float* ws          = (float*)d_ws;
    float* protosum    = ws;
    float* countf      = ws + 25600;
    int*   cnt         = (int*)(ws + 25728);
    float* invf        = ws + 25856;
    float* protoScaled = ws + 34048;

    hipMemsetAsync(d_ws, 0, 25856 * sizeof(float), stream);  // protosum+countf+cnt
    hipMemsetAsync(d_out, 0, sizeof(float), stream);

    k_gather<<<dim3(NCLS, NSPLIT), 256, 0, stream>>>(f, labels, protosum, cnt, invf);
    k_proto<<<NCLS_PAD, 256, 0, stream>>>(protosum, cnt, protoScaled, countf);
    k_main<<<NROWS / BM, 256, 0, stream>>>(f, labels, protoScaled, countf, invf,
                                           (float*)d_out);
}